// Round 1
// baseline (122.841 us; speedup 1.0000x reference)
//
#include <hip/hip_runtime.h>

// KMeans soft-assignment via bf16 hi/lo split MFMA (3 passes), fused softmax.
// logits = (2*x.c - ||c||^2)/T, T=0.1; ||x||^2 cancels in softmax.
// R11: occupancy push. Previous best (R10, 48us/dispatch) was latency-bound:
// MfmaUtil 20 / VALU 22 / HBM 22% with 2 waves/SIMD (130KB LDS -> 1 block/CU,
// AND 236 unified regs -> 2 waves/SIMD). Both limits halved together:
//   BM 128->64, 8 waves = 2 row-groups (wm) x 4 col-groups (wn);
//   per wave 32 rows x 128 cols -> acc[2][8] = 64 regs (keeps the 2-row-group
//   B reuse: 6 MFMA per bh/bl ds_read_b128 pair, LDS pipe stays == MFMA pipe);
//   B single-buffered (64KB) + 33KB lbuf overlay -> ~67KB LDS;
//   __launch_bounds__(512,4) -> 128-reg cap -> 2 blocks/CU (4 waves/SIMD).
// Single buffer costs 2 barriers/K-iter (exposed DMA) -- the co-resident
// block fills that stall and the epilogue HBM-write phase. Co-resident
// blocks start the (accumulation-order-independent) chunk loop 4 apart.
// x: [32768,256] f32, c: [512,256] f32, out: [32768,512] f32
#define NROWS 32768
#define KC 512
#define DDIM 256
#define BM 64
#define BK 32
#define KCH (DDIM / BK)        // 8 k-chunks
#define CHUNK_USH (KC * BK)    // 16384 ushorts = 32 KB per chunk table

typedef __attribute__((ext_vector_type(8))) short bf16x8;
typedef __attribute__((ext_vector_type(4))) float f32x4;

union U8 { unsigned short u[8]; bf16x8 v; };

__device__ __forceinline__ unsigned short f2bf(float f) {   // RNE f32->bf16
    union { float f; unsigned int u; } a; a.f = f;
    unsigned int r = a.u + 0x7fffu + ((a.u >> 16) & 1u);
    return (unsigned short)(r >> 16);
}
__device__ __forceinline__ float bf2f(unsigned short h) {
    union { unsigned int u; float f; } a; a.u = ((unsigned int)h) << 16;
    return a.f;
}
// async global->LDS, 16B/lane; LDS dst must be wave-uniform base + lane*16
__device__ __forceinline__ void ld16(const void* g, void* l) {
    __builtin_amdgcn_global_load_lds(
        (const __attribute__((address_space(1))) unsigned int*)g,
        (__attribute__((address_space(3))) unsigned int*)l, 16, 0, 0);
}

// ---- prep: c -> chunk-major, LDS-swizzle-baked bf16 hi/lo + csq10 ----
// octet (col n, quad q) at chunk offset (n*4 + (q ^ ((n>>1)&3)))*8 ushorts
__global__ __launch_bounds__(64) void prep_c(const float* __restrict__ c,
                                             unsigned short* __restrict__ bhi,
                                             unsigned short* __restrict__ blo,
                                             float* __restrict__ csq10) {
    const int n = blockIdx.x, lane = threadIdx.x;
    const int d0 = lane * 4;
    float4 v = ((const float4*)(c + (size_t)n * DDIM))[lane];
    float vv[4] = {v.x, v.y, v.z, v.w};
    unsigned short hh[4], ll[4];
    float ssq = 0.f;
    #pragma unroll
    for (int i = 0; i < 4; ++i) {
        ssq += vv[i] * vv[i];
        hh[i] = f2bf(vv[i]);
        ll[i] = f2bf(vv[i] - bf2f(hh[i]));
    }
    #pragma unroll
    for (int off = 32; off; off >>= 1) ssq += __shfl_xor(ssq, off);
    if (lane == 0) csq10[n] = 10.f * ssq;
    const int ks = d0 >> 5;
    const int q  = (d0 >> 3) & 3;
    const int s  = q ^ ((n >> 1) & 3);
    const size_t dst = (size_t)ks * CHUNK_USH + (n * 4 + s) * 8 + (d0 & 7);
    *(ushort4*)(bhi + dst) = make_ushort4(hh[0], hh[1], hh[2], hh[3]);
    *(ushort4*)(blo + dst) = make_ushort4(ll[0], ll[1], ll[2], ll[3]);
}

// ---- main: 512 blocks x 512 threads (8 waves = 2 M-groups x 4 N-quarters) ----
union SmemU {
    struct { unsigned short Bh[CHUNK_USH], Bl[CHUNK_USH]; } k;  // 64 KB
    float lbuf[16 * 516];                                        // 33 KB overlay
};

__global__ __launch_bounds__(512, 4) void kmeans_mfma(
    const float* __restrict__ x, const unsigned short* __restrict__ bhi,
    const unsigned short* __restrict__ blo, const float* __restrict__ csq10,
    float* __restrict__ out) {
    __shared__ __align__(16) SmemU sm;
    __shared__ float red[2][4][BM];   // 2 KB

    const int tid  = threadIdx.x;
    const int w    = tid >> 6, lane = tid & 63;
    const int wm   = w >> 2, wn = w & 3;
    const int cc   = lane & 15, q = lane >> 4;
    const int row0 = blockIdx.x * BM;

    f32x4 acc[2][8];
    #pragma unroll
    for (int mt = 0; mt < 2; ++mt)
        #pragma unroll
        for (int t = 0; t < 8; ++t) acc[mt][t] = (f32x4){0.f, 0.f, 0.f, 0.f};

    // A: lane owns rows (row0 + wm*32 + mt*16 + cc), k-octet q*8 per chunk
    const float* xA0 = x + (size_t)(row0 + wm * 32 + cc) * DDIM + q * 8;
    const float* xA1 = xA0 + (size_t)16 * DDIM;
    // B fragment offset within staged chunk (swizzle baked by prep_c)
    const int sF = q ^ ((cc >> 1) & 3);
    const int bF = (4 * cc + sF) * 8;       // + (wn*8+t)*512
    // DMA slots: wave w, j=0..3 -> 1 KB segment (w*4+j)*512 ushorts
    const int dmaOff = w * 2048;

    // stagger co-resident blocks by half the chunk ring (order-independent)
    const int s0 = ((blockIdx.x >> 3) & 1) * 4;

    // ---- prologue: DMA chunk s0; load A(s0) raw ----
    {
        const size_t cb = (size_t)s0 * CHUNK_USH;
        #pragma unroll
        for (int j = 0; j < 4; ++j) {
            const int o = dmaOff + j * 512;
            ld16(bhi + cb + o + lane * 8, &sm.k.Bh[o]);
            ld16(blo + cb + o + lane * 8, &sm.k.Bl[o]);
        }
    }
    const int k0 = s0 * BK;
    float4 c00 = *(const float4*)(xA0 + k0);
    float4 c01 = *(const float4*)(xA0 + k0 + 4);
    float4 c10 = *(const float4*)(xA1 + k0);
    float4 c11 = *(const float4*)(xA1 + k0 + 4);
    __syncthreads();   // DMA drained (implicit vmcnt(0) before barrier)

    for (int i = 0; i < KCH; ++i) {
        const int nks = (s0 + i + 1) & (KCH - 1);
        float4 n00, n01, n10, n11;
        if (i < KCH - 1) {
            const int kn = nks * BK;
            n00 = *(const float4*)(xA0 + kn);
            n01 = *(const float4*)(xA0 + kn + 4);
            n10 = *(const float4*)(xA1 + kn);
            n11 = *(const float4*)(xA1 + kn + 4);
        }
        // convert current A to hi/lo fragments
        bf16x8 ah[2], al[2];
        {
            float v0[8] = {c00.x, c00.y, c00.z, c00.w, c01.x, c01.y, c01.z, c01.w};
            float v1[8] = {c10.x, c10.y, c10.z, c10.w, c11.x, c11.y, c11.z, c11.w};
            U8 H0, L0, H1, L1;
            #pragma unroll
            for (int e = 0; e < 8; ++e) {
                H0.u[e] = f2bf(v0[e]); L0.u[e] = f2bf(v0[e] - bf2f(H0.u[e]));
                H1.u[e] = f2bf(v1[e]); L1.u[e] = f2bf(v1[e] - bf2f(H1.u[e]));
            }
            ah[0] = H0.v; al[0] = L0.v; ah[1] = H1.v; al[1] = L1.v;
        }
        // MFMA over staged buffer: 2 LDS reads feed 6 MFMAs
        #pragma unroll
        for (int t = 0; t < 8; ++t) {
            const int bo = (wn * 8 + t) * 512 + bF;
            bf16x8 bh = *(const bf16x8*)&sm.k.Bh[bo];
            bf16x8 bl = *(const bf16x8*)&sm.k.Bl[bo];
            acc[0][t] = __builtin_amdgcn_mfma_f32_16x16x32_bf16(ah[0], bh, acc[0][t], 0, 0, 0);
            acc[1][t] = __builtin_amdgcn_mfma_f32_16x16x32_bf16(ah[1], bh, acc[1][t], 0, 0, 0);
            acc[0][t] = __builtin_amdgcn_mfma_f32_16x16x32_bf16(ah[0], bl, acc[0][t], 0, 0, 0);
            acc[1][t] = __builtin_amdgcn_mfma_f32_16x16x32_bf16(ah[1], bl, acc[1][t], 0, 0, 0);
            acc[0][t] = __builtin_amdgcn_mfma_f32_16x16x32_bf16(al[0], bh, acc[0][t], 0, 0, 0);
            acc[1][t] = __builtin_amdgcn_mfma_f32_16x16x32_bf16(al[1], bh, acc[1][t], 0, 0, 0);
        }
        __syncthreads();   // all waves done reading the single buffer
        if (i < KCH - 1) {
            const size_t cb = (size_t)nks * CHUNK_USH;
            #pragma unroll
            for (int j = 0; j < 4; ++j) {
                const int o = dmaOff + j * 512;
                ld16(bhi + cb + o + lane * 8, &sm.k.Bh[o]);
                ld16(blo + cb + o + lane * 8, &sm.k.Bl[o]);
            }
            __syncthreads();   // DMA drained; co-resident block hides this
        }
        c00 = n00; c01 = n01; c10 = n10; c11 = n11;
    }

    // ---- softmax stats: reduce over t, then cc-lanes, then 4 wn groups ----
    float csqv[8];
    #pragma unroll
    for (int t = 0; t < 8; ++t) csqv[t] = csq10[wn * 128 + t * 16 + cc];
    const int rb = wm * 32 + q * 4;   // + mt*16 + g
    float M[2][4], I[2][4];
    #pragma unroll
    for (int mt = 0; mt < 2; ++mt)
        #pragma unroll
        for (int g = 0; g < 4; ++g) {
            float pm = -1e30f;
            #pragma unroll
            for (int t = 0; t < 8; ++t) pm = fmaxf(pm, 20.f * acc[mt][t][g] - csqv[t]);
            #pragma unroll
            for (int off = 1; off < 16; off <<= 1) pm = fmaxf(pm, __shfl_xor(pm, off));
            if (cc == 0) red[0][wn][rb + mt * 16 + g] = pm;
        }
    __syncthreads();
    #pragma unroll
    for (int mt = 0; mt < 2; ++mt)
        #pragma unroll
        for (int g = 0; g < 4; ++g) {
            const int ri = rb + mt * 16 + g;
            const float m = fmaxf(fmaxf(red[0][0][ri], red[0][1][ri]),
                                  fmaxf(red[0][2][ri], red[0][3][ri]));
            M[mt][g] = m;
            float ps = 0.f;
            #pragma unroll
            for (int t = 0; t < 8; ++t) ps += __expf(20.f * acc[mt][t][g] - csqv[t] - m);
            #pragma unroll
            for (int off = 1; off < 16; off <<= 1) ps += __shfl_xor(ps, off);
            if (cc == 0) red[1][wn][ri] = ps;
        }
    __syncthreads();
    #pragma unroll
    for (int mt = 0; mt < 2; ++mt)
        #pragma unroll
        for (int g = 0; g < 4; ++g) {
            const int ri = rb + mt * 16 + g;
            I[mt][g] = 1.f / (red[1][0][ri] + red[1][1][ri] +
                              red[1][2][ri] + red[1][3][ri]);
        }

    // ---- transpose epilogue: 4 passes of 16 rows through lbuf, dense stores ----
    #pragma unroll
    for (int p = 0; p < 4; ++p) {
        if (wm == (p >> 1)) {
            const int mt = p & 1;
            #pragma unroll
            for (int g = 0; g < 4; ++g) {
                const int   lr = q * 4 + g;
                const float mg = M[mt][g], ig = I[mt][g];
                #pragma unroll
                for (int t = 0; t < 8; ++t)
                    sm.lbuf[lr * 516 + wn * 128 + t * 16 + cc] =
                        __expf(20.f * acc[mt][t][g] - csqv[t] - mg) * ig;
            }
        }
        __syncthreads();
        #pragma unroll
        for (int j = 0; j < 4; ++j) {
            const int f    = j * 512 + tid;     // 0..2047 float4 slots
            const int lrow = f >> 7;            // 0..15
            const int c4   = f & 127;
            float4    v    = *(const float4*)&sm.lbuf[lrow * 516 + c4 * 4];
            *(float4*)(out + (size_t)(row0 + p * 16 + lrow) * KC + c4 * 4) = v;
        }
        __syncthreads();
    }
}

extern "C" void kernel_launch(void* const* d_in, const int* in_sizes, int n_in,
                              void* d_out, int out_size, void* d_ws, size_t ws_size,
                              hipStream_t stream) {
    const float* x   = (const float*)d_in[0];
    const float* c   = (const float*)d_in[1];
    float*       out = (float*)d_out;

    unsigned short* bhi   = (unsigned short*)d_ws;                 // 256 KB
    unsigned short* blo   = bhi + (size_t)KCH * CHUNK_USH;         // 256 KB
    float*          csq10 = (float*)(blo + (size_t)KCH * CHUNK_USH);  // 2 KB

    prep_c<<<KC, 64, 0, stream>>>(c, bhi, blo, csq10);
    kmeans_mfma<<<NROWS / BM, 512, 0, stream>>>(x, bhi, blo, csq10, out);
}